// Round 8
// baseline (8115.228 us; speedup 1.0000x reference)
//
#include <hip/hip_runtime.h>
#include <hip/hip_bf16.h>
#include <cstdint>
#include <cstddef>

// Problem constants
#define TT 1024
#define BB 32
#define DD 1024
#define HH 512
#define GG 2048  // 4H

// f16 -inf bit pattern replicated; |h|<1 so a valid packed h can never be it
#define POISON_U64 0xFC00FC00FC00FC00ull

typedef _Float16 f16x8 __attribute__((ext_vector_type(8)));
typedef _Float16 f16x4 __attribute__((ext_vector_type(4)));
typedef float    f32x4 __attribute__((ext_vector_type(4)));

__device__ __forceinline__ float sigm(float x) { return 1.0f / (1.0f + __expf(-x)); }
__device__ __forceinline__ float tanh_fast(float x) { return 2.0f / (1.0f + __expf(-2.0f * x)) - 1.0f; }

// ---------------------------------------------------------------------------
// init: hring = [dir][grp][slot4][2048] u64, each u64 = 4xf16 h data.
// Slot for step s is s&3. Slot 0 = h(0) = all-zero (valid: low f16 = 0 !=
// poison). Slots 1..3 = poison. 2*2*4*2048 = 32768 u64 -> 128 x 256.
// ---------------------------------------------------------------------------
__global__ __launch_bounds__(256) void init_kernel(unsigned long long* __restrict__ hr) {
    const int i = blockIdx.x * 256 + threadIdx.x;
    const int slot = (i >> 11) & 3;
    hr[i] = (slot == 0) ? 0ull : POISON_U64;
}

// ---------------------------------------------------------------------------
// transpose_f16: in fp32 [K][N] row-major -> out f16 [N][K].
// ---------------------------------------------------------------------------
__global__ __launch_bounds__(256) void transpose_f16(const float* __restrict__ in,
                                                     _Float16* __restrict__ out,
                                                     int K, int N) {
    __shared__ float tile[32][33];
    const int tx = threadIdx.x & 31, ty = threadIdx.x >> 5;
    const int n0 = blockIdx.x * 32, k0 = blockIdx.y * 32;
#pragma unroll
    for (int j = 0; j < 4; j++)
        tile[ty + 8 * j][tx] = in[(size_t)(k0 + ty + 8 * j) * N + n0 + tx];
    __syncthreads();
#pragma unroll
    for (int j = 0; j < 4; j++)
        out[(size_t)(n0 + ty + 8 * j) * K + k0 + tx] = (_Float16)tile[tx][ty + 8 * j];
}

// ---------------------------------------------------------------------------
// Phase 1: xg = x@Wx + b via MFMA f16 (fp32 accumulate), stored f16.
// (EXACT R4 version — best measured; R6 dual-dir fuse regressed.)
// Output layout (recurrence/chunk-native), indexed by recurrence STEP sidx
// (sidx = t for fwd, 1023-t for bwd):
//   xgv[blk32][b32][jl16][sc128][si8][g4]
//   idx = ((((blk*32+b)*16+jl)*128 + sc)*8 + si)*4 + g
// Block covers ALL 4 GATES x 32 hidden cols; epilogue assembles contiguous
// (4 si x 4 g) = 32 B runs in LDS, emits 2x16B vector stores.
// ---------------------------------------------------------------------------
__global__ __launch_bounds__(256) void gemm_xg(const float* __restrict__ x,
                                               const _Float16* __restrict__ WxT_f,
                                               const float* __restrict__ b_f,
                                               const _Float16* __restrict__ WxT_b,
                                               const float* __restrict__ b_b,
                                               _Float16* __restrict__ xg_f,
                                               _Float16* __restrict__ xg_b) {
    const int dir = blockIdx.z;
    const _Float16* __restrict__ WxT = dir ? WxT_b : WxT_f;
    const float* __restrict__ bias = dir ? b_b : b_f;
    _Float16* __restrict__ out = dir ? xg_b : xg_f;

    const int c0 = blockIdx.x * 32;   // hidden-col base (0..511)
    const int m0 = blockIdx.y * 128;  // row base; t0 = blockIdx.y*4

    __shared__ __align__(16) unsigned char smem[40960];
    _Float16* A_lds = (_Float16*)smem;            // [128][72]
    _Float16* B_lds = (_Float16*)(smem + 18432);  // [128][72]
    _Float16* stage = (_Float16*)smem;            // [c32][520]: b*16 + lsi*4 + g

    const int tid = threadIdx.x;
    const int wave = tid >> 6;
    const int lane = tid & 63;
    const int jn = lane & 15;
    const int quad = lane >> 4;

    f32x4 acc[2][8] = {};

    for (int k0 = 0; k0 < DD; k0 += 64) {
        // ---- stage A: 128m x 64k fp32 -> f16 LDS ----
        {
            const int kq = tid & 15;
            const int mq = tid >> 4;
#pragma unroll
            for (int i = 0; i < 8; i++) {
                const int m = mq + 16 * i;
                const int gm = m0 + m;
                const int t = gm >> 5;
                const int b = gm & 31;
                const float4 v = *(const float4*)(x + ((size_t)b * TT + t) * DD + k0 + kq * 4);
                f16x4 f;
                f.x = (_Float16)v.x; f.y = (_Float16)v.y;
                f.z = (_Float16)v.z; f.w = (_Float16)v.w;
                *(f16x4*)(A_lds + m * 72 + kq * 4) = f;
            }
        }
        // ---- stage B: 128 rows = {g*512 + c0 + c : g 0..3, c 0..31} ----
        {
            const int kq = tid & 7;
            const int nq = tid >> 3;
#pragma unroll
            for (int i = 0; i < 4; i++) {
                const int nl = nq + 32 * i;   // 0..127: g = nl>>5, c = nl&31
                const int g = nl >> 5;
                const int c = nl & 31;
                f16x8 w = *(const f16x8*)(WxT + (size_t)(g * 512 + c0 + c) * DD + k0 + kq * 8);
                *(f16x8*)(B_lds + nl * 72 + kq * 8) = w;
            }
        }
        __syncthreads();
#pragma unroll
        for (int kc = 0; kc < 64; kc += 32) {
            const f16x8 a0 = *(const f16x8*)(A_lds + (wave * 32 + jn) * 72 + kc + quad * 8);
            const f16x8 a1 = *(const f16x8*)(A_lds + (wave * 32 + 16 + jn) * 72 + kc + quad * 8);
#pragma unroll
            for (int nt = 0; nt < 8; nt++) {
                const f16x8 bb = *(const f16x8*)(B_lds + (nt * 16 + jn) * 72 + kc + quad * 8);
                acc[0][nt] = __builtin_amdgcn_mfma_f32_16x16x32_f16(a0, bb, acc[0][nt], 0, 0, 0);
                acc[1][nt] = __builtin_amdgcn_mfma_f32_16x16x32_f16(a1, bb, acc[1][nt], 0, 0, 0);
            }
        }
        __syncthreads();
    }

    // ---- epilogue: bias, assemble (si,g) runs in LDS, 16B vector stores ----
    float bv[8];
#pragma unroll
    for (int nt = 0; nt < 8; nt++)
        bv[nt] = bias[(nt >> 1) * 512 + c0 + (nt & 1) * 16 + jn];

    const int lsi = dir ? (3 - wave) : wave;
#pragma unroll
    for (int mt = 0; mt < 2; mt++) {
#pragma unroll
        for (int r = 0; r < 4; r++) {
            const int b = mt * 16 + quad * 4 + r;
#pragma unroll
            for (int nt = 0; nt < 8; nt++) {
                const int c = (nt & 1) * 16 + jn;
                stage[c * 520 + b * 16 + lsi * 4 + (nt >> 1)] =
                    (_Float16)(acc[mt][nt][r] + bv[nt]);
            }
        }
    }
    __syncthreads();

    const int sidx0 = dir ? (1020 - blockIdx.y * 4) : (blockIdx.y * 4);
    const int sc = sidx0 >> 3;
    const int si0 = sidx0 & 7;  // 0 or 4
#pragma unroll
    for (int it = 0; it < 4; it++) {
        const int p = it * 256 + tid;
        const int c = p & 31;
        const int b = p >> 5;
        const int cglob = c0 + c;
        const int blk = cglob >> 4;
        const int jl = cglob & 15;
        const f16x8* srcp = (const f16x8*)(stage + c * 520 + b * 16);
        const size_t obase =
            ((((size_t)(blk * 32 + b) * 16 + jl) * 128 + sc) * 8 + si0) * 4;
        *(f16x8*)(out + obase) = srcp[0];
        *(f16x8*)(out + obase + 8) = srcp[1];
    }
}

// ---------------------------------------------------------------------------
// Phase 2: persistent bidirectional LSTM recurrence via MFMA.
// R8: DUAL-ROLE blocks — 32 blocks x 512 threads; block (grp, blk) owns
// BOTH the fwd and bwd role for its (grp, blk) and ALTERNATES f-step /
// b-step. While chain f's h-store propagates through IF$, the block
// computes the entire b step (and vice versa) — the chain's store->
// visibility->discovery latency is hidden under the other direction's
// compute instead of sitting naked on the critical path.
//
// Chains unchanged from R4 (the measured fan-in optimum): 4 chains
// (dir x grp), 16 blocks each; grp owns batch rows [grp*16, +16); block
// owns hidden cols [blk*32, +32) x 4 gates. Per-chain protocol IDENTICAL
// to R4 (4 passing rounds): sentinel-poisoned 4-slot ring, 4xf16/u64,
// validity = low f16 != 0xFC00; producer re-poisons its own (s-2) slots
// before the post-poll barrier (vmcnt-0 drain orders poison before this
// sub-step's h(s+1) store; IF$ = single agent-scope coherence point).
//
// Shared h_lds / red across the two halves is safe: stage_b comes after
// BAR2 (> MFMA_f h_lds reads); MFMA_b red writes after BAR3 (> gate_f
// red reads); next-iter stage_f after BAR4 (> MFMA_b reads). 2 barriers
// per step, same as R4.
// ---------------------------------------------------------------------------
__global__ __launch_bounds__(512, 2) void lstm_persist(
    const _Float16* __restrict__ xg_f,
    const _Float16* __restrict__ xg_b,
    const _Float16* __restrict__ WhT_f,
    const _Float16* __restrict__ WhT_b,
    const float* __restrict__ wfc,
    unsigned long long* __restrict__ hring,   // [dir][grp][slot4][2048] u64
    _Float16* __restrict__ part) {

    __shared__ __align__(16) _Float16 h_lds[16 * 520];  // [row16][k512 pad 520]
    __shared__ float red[4 * 16 * 33];                  // [g][row16][col32 pad 33]

    const int tid = threadIdx.x;
    const int bid = blockIdx.x;   // 0..31
    const int grp = bid >> 4;     // 0..1
    const int blk = bid & 15;     // 0..15

    // wave roles
    const int lane = tid & 63;
    const int wave = tid >> 6;
    const int g = wave >> 1;       // gate 0..3
    const int half = wave & 1;     // hidden-16 half within block's 32 cols
    const int jl16 = lane & 15;
    const int quad = lane >> 4;

    // ---- preload Wh B-fragments for BOTH dirs (once): 2 x 64 VGPR ----
    f16x8 bfrag[2][16];
#pragma unroll
    for (int d = 0; d < 2; d++) {
        const _Float16* __restrict__ WhT = d ? WhT_b : WhT_f;
        const _Float16* wcol = WhT + (size_t)(g * 512 + blk * 32 + half * 16 + jl16) * HH;
#pragma unroll
        for (int i = 0; i < 16; i++)
            bfrag[d][i] = *(const f16x8*)(wcol + i * 32 + quad * 8);
    }

    // gate-thread role: one (row, col) per thread
    const int gb = tid >> 5;       // row within group, 0..15
    const int gc = tid & 31;       // hidden col within block's 32
    float c_reg[2] = {0.0f, 0.0f};
    float wfc_reg[2];
    wfc_reg[0] = wfc[0 * 512 + blk * 32 + gc];
    wfc_reg[1] = wfc[1 * 512 + blk * 32 + gc];

    unsigned long long* hl64 = (unsigned long long*)h_lds;
    const int blk32 = blk * 2 + (gc >> 4);
    const int b_glob = grp * 16 + gb;
    const _Float16* xbase[2];
    xbase[0] = xg_f + (((size_t)(blk32 * 32 + b_glob) * 16 + (gc & 15)) * 128) * 32;
    xbase[1] = xg_b + (((size_t)(blk32 * 32 + b_glob) * 16 + (gc & 15)) * 128) * 32;
    unsigned long long* hp[2];
    hp[0] = hring + ((size_t)(0 * 2 + grp)) * 8192;  // [slot4][2048]
    hp[1] = hring + ((size_t)(1 * 2 + grp)) * 8192;

    // producer slot (threads with gc%4==0): u64 covers cols blk*32+gc..+3
    const int prod_idx = gb * 128 + blk * 8 + (gc >> 2);
    const bool is_prod = ((gc & 3) == 0);

    // ---- xg chunk double-buffer (both dirs): 2x64 B regs / 8 steps ----
    f16x8 xcur[2][4];
#pragma unroll
    for (int d = 0; d < 2; d++) {
        const f16x8* src0 = (const f16x8*)(xbase[d]);
#pragma unroll
        for (int q = 0; q < 4; q++) xcur[d][q] = src0[q];
    }

    for (int sc = 0; sc < 128; sc++) {
        f16x8 xnxt[2][4];
        if (sc < 127) {
#pragma unroll
            for (int d = 0; d < 2; d++) {
                const f16x8* srcn = (const f16x8*)(xbase[d] + (sc + 1) * 32);
#pragma unroll
                for (int q = 0; q < 4; q++) xnxt[d][q] = srcn[q];
            }
        }

#pragma unroll
        for (int si = 0; si < 8; si++) {
            const int s = sc * 8 + si;

#pragma unroll
            for (int d = 0; d < 2; d++) {
                const int t = d ? (1023 - s) : s;

                // ---- re-poison own step-(s-2) positions (chain d) ----
                if (s >= 2 && is_prod)
                    __hip_atomic_store(hp[d] + (size_t)((s - 2) & 3) * 2048 + prod_idx,
                                       POISON_U64, __ATOMIC_RELAXED,
                                       __HIP_MEMORY_SCOPE_AGENT);

                // ---- stage h_d(s): poll sentinel u64s -> LDS (R4 form) ----
                {
                    const unsigned long long* __restrict__ src =
                        hp[d] + (size_t)(s & 3) * 2048;
                    unsigned int pend = 0xFu;
                    int guard = 0;
                    do {
                        unsigned long long v[4];
#pragma unroll
                        for (int q = 0; q < 4; q++)
                            if (pend & (1u << q))
                                v[q] = __hip_atomic_load(src + q * 512 + tid,
                                                         __ATOMIC_RELAXED,
                                                         __HIP_MEMORY_SCOPE_AGENT);
                        unsigned int got = 0;
#pragma unroll
                        for (int q = 0; q < 4; q++) {
                            if ((pend & (1u << q)) &&
                                ((unsigned int)v[q] & 0xFFFFu) != 0xFC00u) {
                                const int idx = q * 512 + tid;
                                hl64[(idx >> 7) * 130 + (idx & 127)] = v[q];
                                got |= (1u << q);
                            }
                        }
                        pend &= ~got;
                        if (pend) {
                            if (got == 0) __builtin_amdgcn_s_sleep(1);
                            if (++guard > (1 << 18)) break;  // fail visibly
                        }
                    } while (pend);
                }
                __syncthreads();

                // ---- MFMA: preact [16row x 16col], 4 independent chains ----
                {
                    f32x4 a0 = {0.f, 0.f, 0.f, 0.f};
                    f32x4 a1 = {0.f, 0.f, 0.f, 0.f};
                    f32x4 a2 = {0.f, 0.f, 0.f, 0.f};
                    f32x4 a3 = {0.f, 0.f, 0.f, 0.f};
                    const _Float16* hrow = h_lds + jl16 * 520 + quad * 8;
#pragma unroll
                    for (int i = 0; i < 4; i++) {
                        const f16x8 h0 = *(const f16x8*)(hrow + 32 * i);
                        const f16x8 h1 = *(const f16x8*)(hrow + 32 * (i + 4));
                        const f16x8 h2 = *(const f16x8*)(hrow + 32 * (i + 8));
                        const f16x8 h3 = *(const f16x8*)(hrow + 32 * (i + 12));
                        a0 = __builtin_amdgcn_mfma_f32_16x16x32_f16(h0, bfrag[d][i],      a0, 0, 0, 0);
                        a1 = __builtin_amdgcn_mfma_f32_16x16x32_f16(h1, bfrag[d][i + 4],  a1, 0, 0, 0);
                        a2 = __builtin_amdgcn_mfma_f32_16x16x32_f16(h2, bfrag[d][i + 8],  a2, 0, 0, 0);
                        a3 = __builtin_amdgcn_mfma_f32_16x16x32_f16(h3, bfrag[d][i + 12], a3, 0, 0, 0);
                    }
                    const f32x4 acc = (a0 + a1) + (a2 + a3);
#pragma unroll
                    for (int r = 0; r < 4; r++)
                        red[(g * 16 + quad * 4 + r) * 33 + half * 16 + jl16] = acc[r];
                }
                __syncthreads();

                // ---- gate math + h/c update + sentinel store + FC partial ----
                {
                    const float p0 = red[(0 * 16 + gb) * 33 + gc] + (float)xcur[d][si >> 1][(si & 1) * 4 + 0];
                    const float p1 = red[(1 * 16 + gb) * 33 + gc] + (float)xcur[d][si >> 1][(si & 1) * 4 + 1];
                    const float p2 = red[(2 * 16 + gb) * 33 + gc] + (float)xcur[d][si >> 1][(si & 1) * 4 + 2];
                    const float p3 = red[(3 * 16 + gb) * 33 + gc] + (float)xcur[d][si >> 1][(si & 1) * 4 + 3];

                    const float gi = sigm(p0);
                    const float gf = sigm(p1);
                    const float gc_ = tanh_fast(p2);
                    const float go = sigm(p3);
                    c_reg[d] = gf * c_reg[d] + gi * gc_;
                    const float hval = go * tanh_fast(c_reg[d]);

                    // pack 4 consecutive cols into one u64 (two shfls), ONE
                    // relaxed agent store per 4 lanes.
                    const float hnb = __shfl_xor(hval, 1);
                    union { struct { _Float16 lo, hi; } h; unsigned int u; } cvt;
                    cvt.h.lo = (_Float16)hval;
                    cvt.h.hi = (_Float16)hnb;
                    const unsigned int pair2 = __shfl_xor(cvt.u, 2);
                    if (is_prod) {
                        const unsigned long long pv =
                            ((unsigned long long)pair2 << 32) | (unsigned long long)cvt.u;
                        __hip_atomic_store(hp[d] + (size_t)((s + 1) & 3) * 2048 + prod_idx, pv,
                                           __ATOMIC_RELAXED, __HIP_MEMORY_SCOPE_AGENT);
                    }
                    // FC partial: reduce over this block's 32 cols
                    float contrib = hval * wfc_reg[d];
                    contrib += __shfl_xor(contrib, 1);
                    contrib += __shfl_xor(contrib, 2);
                    contrib += __shfl_xor(contrib, 4);
                    contrib += __shfl_xor(contrib, 8);
                    contrib += __shfl_xor(contrib, 16);
                    if (gc == 0)
                        part[(size_t)(t * 32 + b_glob) * 32 + d * 16 + blk] = (_Float16)contrib;
                }
                // no trailing barrier: the next sub-step's LDS stage writes
                // are ordered after this sub-step's reads by the barriers
                // above (see header comment).
            }
        }

        if (sc < 127) {
#pragma unroll
            for (int d = 0; d < 2; d++)
#pragma unroll
                for (int q = 0; q < 4; q++) xcur[d][q] = xnxt[d][q];
        }
    }
}

// ---------------------------------------------------------------------------
// Final: out[b][t] = sigmoid(b_fc + sum over 32 partials part[t][b][*])
// ---------------------------------------------------------------------------
__global__ __launch_bounds__(256) void fc_final(const _Float16* __restrict__ part,
                                                const float* __restrict__ b_fc,
                                                float* __restrict__ out) {
    const int i = blockIdx.x * 256 + threadIdx.x;  // i = b*1024 + t
    const int b = i >> 10;
    const int t = i & 1023;
    const f16x8* p = (const f16x8*)(part + (size_t)(t * 32 + b) * 32);
    float acc = b_fc[0];
#pragma unroll
    for (int q = 0; q < 4; q++) {
        const f16x8 v = p[q];
#pragma unroll
        for (int e = 0; e < 8; e++) acc += (float)v[e];
    }
    out[i] = sigm(acc);
}

extern "C" void kernel_launch(void* const* d_in, const int* in_sizes, int n_in,
                              void* d_out, int out_size, void* d_ws, size_t ws_size,
                              hipStream_t stream) {
    const float* x    = (const float*)d_in[0];
    const float* Wx_f = (const float*)d_in[1];
    const float* Wh_f = (const float*)d_in[2];
    const float* b_f  = (const float*)d_in[3];
    const float* Wx_b = (const float*)d_in[4];
    const float* Wh_b = (const float*)d_in[5];
    const float* b_b  = (const float*)d_in[6];
    const float* W_fc = (const float*)d_in[7];
    const float* b_fc = (const float*)d_in[8];
    float* out = (float*)d_out;

    // Workspace layout (bytes):
    //   xgv_f f16 chunk-native          : 134,217,728
    //   xgv_b f16 chunk-native          : 134,217,728
    //   WxT_f f16 [2048][1024]          : 4,194,304   <- `part` (2 MB) aliases
    //                                                    this after gemm_xg
    //   WxT_b f16 [2048][1024]          : 4,194,304   <- hring (256 KB)
    //                                                    aliases this after gemm_xg
    //   WhT_f f16 [2048][512]           : 2,097,152
    //   WhT_b f16 [2048][512]           : 2,097,152
    // total 281,018,368 (same as previous passing rounds).
    // Order: transposes -> gemm_xg -> init (poisons hring in dead WxT_b) ->
    //        lstm_persist -> fc_final.
    const size_t XG       = 134217728ULL;
    const size_t WXT_OFF  = 2 * XG;                        // 268,435,456
    const size_t WHT_OFF  = WXT_OFF + 2 * 4194304ULL;      // 276,824,064
    const size_t need     = WHT_OFF + 2 * 2097152ULL;      // 281,018,368
    if (ws_size < need) return;  // fail loudly via mismatch

    uint8_t* ws = (uint8_t*)d_ws;
    _Float16* xg_f = (_Float16*)ws;
    _Float16* xg_b = (_Float16*)(ws + XG);
    _Float16* WxT_f = (_Float16*)(ws + WXT_OFF);
    _Float16* WxT_b = (_Float16*)(ws + WXT_OFF + 4194304ULL);
    _Float16* WhT_f = (_Float16*)(ws + WHT_OFF);
    _Float16* WhT_b = (_Float16*)(ws + WHT_OFF + 2097152ULL);
    _Float16* part  = (_Float16*)(ws + WXT_OFF);                 // alias WxT_f
    unsigned long long* hring =
        (unsigned long long*)(ws + WXT_OFF + 4194304ULL);        // alias WxT_b

    // pre-transpose weights to f16 [n][k]
    transpose_f16<<<dim3(64, 32), 256, 0, stream>>>(Wx_f, WxT_f, 1024, 2048);
    transpose_f16<<<dim3(64, 32), 256, 0, stream>>>(Wx_b, WxT_b, 1024, 2048);
    transpose_f16<<<dim3(64, 16), 256, 0, stream>>>(Wh_f, WhT_f, 512, 2048);
    transpose_f16<<<dim3(64, 16), 256, 0, stream>>>(Wh_b, WhT_b, 512, 2048);

    // phase 1: input projections (MFMA f16), R4 split-dir grid
    gemm_xg<<<dim3(16, 256, 2), 256, 0, stream>>>(
        x, WxT_f, b_f, WxT_b, b_b, xg_f, xg_b);

    // init sentinel rings (4 chains; slot0 = zeros = valid h(0)) — after
    // gemm_xg since it aliases WxT_b
    init_kernel<<<128, 256, 0, stream>>>(hring);

    // phase 2: persistent recurrence (32 dual-role blocks = 4 chains x 16)
    lstm_persist<<<32, 512, 0, stream>>>(
        xg_f, xg_b, WhT_f, WhT_b, W_fc, hring, part);

    // epilogue: reduce FC partials + bias + sigmoid
    fc_final<<<(BB * TT) / 256, 256, 0, stream>>>(part, b_fc, out);
}

// Round 9
// 3350.363 us; speedup vs baseline: 2.4222x; 2.4222x over previous
//
#include <hip/hip_runtime.h>
#include <hip/hip_bf16.h>
#include <cstdint>
#include <cstddef>

// Problem constants
#define TT 1024
#define BB 32
#define DD 1024
#define HH 512
#define GG 2048  // 4H

// f16 -inf bit pattern replicated; |h|<1 so a valid packed h can never be it
#define POISON_U64 0xFC00FC00FC00FC00ull

typedef _Float16 f16x8 __attribute__((ext_vector_type(8)));
typedef _Float16 f16x4 __attribute__((ext_vector_type(4)));
typedef float    f32x4 __attribute__((ext_vector_type(4)));

__device__ __forceinline__ float sigm(float x) { return 1.0f / (1.0f + __expf(-x)); }
__device__ __forceinline__ float tanh_fast(float x) { return 2.0f / (1.0f + __expf(-2.0f * x)) - 1.0f; }

// ---------------------------------------------------------------------------
// init: hring = [dir][grp][slot4][2048] u64, each u64 = 4xf16 h data.
// Slot for step s is s&3. Slot 0 = h(0) = all-zero (valid: low f16 = 0 !=
// poison). Slots 1..3 = poison. 2*2*4*2048 = 32768 u64 -> 128 x 256.
// ---------------------------------------------------------------------------
__global__ __launch_bounds__(256) void init_kernel(unsigned long long* __restrict__ hr) {
    const int i = blockIdx.x * 256 + threadIdx.x;
    const int slot = (i >> 11) & 3;
    hr[i] = (slot == 0) ? 0ull : POISON_U64;
}

// ---------------------------------------------------------------------------
// conv_x: x fp32 [B][T][D] -> x16 f16 same layout (one pass, ~30 us).
// 8,388,608 float4s; 8192 blocks x 256 threads x 4 each.
// ---------------------------------------------------------------------------
__global__ __launch_bounds__(256) void conv_x(const float* __restrict__ x,
                                              _Float16* __restrict__ x16) {
    const int gid = blockIdx.x * 256 + threadIdx.x;
#pragma unroll
    for (int i = 0; i < 4; i++) {
        const size_t idx = (size_t)(gid * 4 + i);
        const float4 v = *(const float4*)(x + idx * 4);
        f16x4 f;
        f.x = (_Float16)v.x; f.y = (_Float16)v.y;
        f.z = (_Float16)v.z; f.w = (_Float16)v.w;
        *(f16x4*)(x16 + idx * 4) = f;
    }
}

// ---------------------------------------------------------------------------
// transpose_f16: in fp32 [K][N] row-major -> out f16 [N][K].
// ---------------------------------------------------------------------------
__global__ __launch_bounds__(256) void transpose_f16(const float* __restrict__ in,
                                                     _Float16* __restrict__ out,
                                                     int K, int N) {
    __shared__ float tile[32][33];
    const int tx = threadIdx.x & 31, ty = threadIdx.x >> 5;
    const int n0 = blockIdx.x * 32, k0 = blockIdx.y * 32;
#pragma unroll
    for (int j = 0; j < 4; j++)
        tile[ty + 8 * j][tx] = in[(size_t)(k0 + ty + 8 * j) * N + n0 + tx];
    __syncthreads();
#pragma unroll
    for (int j = 0; j < 4; j++)
        out[(size_t)(n0 + ty + 8 * j) * K + k0 + tx] = (_Float16)tile[tx][ty + 8 * j];
}

// ---------------------------------------------------------------------------
// Phase 1: xg = x@Wx + b via MFMA f16 (fp32 accumulate), stored f16.
// (R4 structure — best measured. R9: optional f16 A-path when x16 != null:
// stage-A becomes pure 16B f16 copies, halving staging VALU and A traffic.)
// Output layout (recurrence/chunk-native), indexed by recurrence STEP sidx
// (sidx = t for fwd, 1023-t for bwd):
//   xgv[blk32][b32][jl16][sc128][si8][g4]
//   idx = ((((blk*32+b)*16+jl)*128 + sc)*8 + si)*4 + g
// Block covers ALL 4 GATES x 32 hidden cols; epilogue assembles contiguous
// (4 si x 4 g) = 32 B runs in LDS, emits 2x16B vector stores.
// ---------------------------------------------------------------------------
__global__ __launch_bounds__(256) void gemm_xg(const float* __restrict__ x,
                                               const _Float16* __restrict__ x16,
                                               const _Float16* __restrict__ WxT_f,
                                               const float* __restrict__ b_f,
                                               const _Float16* __restrict__ WxT_b,
                                               const float* __restrict__ b_b,
                                               _Float16* __restrict__ xg_f,
                                               _Float16* __restrict__ xg_b) {
    const int dir = blockIdx.z;
    const _Float16* __restrict__ WxT = dir ? WxT_b : WxT_f;
    const float* __restrict__ bias = dir ? b_b : b_f;
    _Float16* __restrict__ out = dir ? xg_b : xg_f;

    const int c0 = blockIdx.x * 32;   // hidden-col base (0..511)
    const int m0 = blockIdx.y * 128;  // row base; t0 = blockIdx.y*4

    __shared__ __align__(16) unsigned char smem[40960];
    _Float16* A_lds = (_Float16*)smem;            // [128][72]
    _Float16* B_lds = (_Float16*)(smem + 18432);  // [128][72]
    _Float16* stage = (_Float16*)smem;            // [c32][520]: b*16 + lsi*4 + g

    const int tid = threadIdx.x;
    const int wave = tid >> 6;
    const int lane = tid & 63;
    const int jn = lane & 15;
    const int quad = lane >> 4;

    f32x4 acc[2][8] = {};

    for (int k0 = 0; k0 < DD; k0 += 64) {
        // ---- stage A: 128m x 64k -> f16 LDS ----
        if (x16) {
            // f16 path: pure 16B copies
            const int kq = tid & 7;
            const int mq = tid >> 3;
#pragma unroll
            for (int i = 0; i < 4; i++) {
                const int m = mq + 32 * i;
                const int gm = m0 + m;
                const int t = gm >> 5;
                const int b = gm & 31;
                const f16x8 v = *(const f16x8*)(x16 + ((size_t)b * TT + t) * DD + k0 + kq * 8);
                *(f16x8*)(A_lds + m * 72 + kq * 8) = v;
            }
        } else {
            // fp32 fallback (R4 exact)
            const int kq = tid & 15;
            const int mq = tid >> 4;
#pragma unroll
            for (int i = 0; i < 8; i++) {
                const int m = mq + 16 * i;
                const int gm = m0 + m;
                const int t = gm >> 5;
                const int b = gm & 31;
                const float4 v = *(const float4*)(x + ((size_t)b * TT + t) * DD + k0 + kq * 4);
                f16x4 f;
                f.x = (_Float16)v.x; f.y = (_Float16)v.y;
                f.z = (_Float16)v.z; f.w = (_Float16)v.w;
                *(f16x4*)(A_lds + m * 72 + kq * 4) = f;
            }
        }
        // ---- stage B: 128 rows = {g*512 + c0 + c : g 0..3, c 0..31} ----
        {
            const int kq = tid & 7;
            const int nq = tid >> 3;
#pragma unroll
            for (int i = 0; i < 4; i++) {
                const int nl = nq + 32 * i;   // 0..127: g = nl>>5, c = nl&31
                const int g = nl >> 5;
                const int c = nl & 31;
                f16x8 w = *(const f16x8*)(WxT + (size_t)(g * 512 + c0 + c) * DD + k0 + kq * 8);
                *(f16x8*)(B_lds + nl * 72 + kq * 8) = w;
            }
        }
        __syncthreads();
#pragma unroll
        for (int kc = 0; kc < 64; kc += 32) {
            const f16x8 a0 = *(const f16x8*)(A_lds + (wave * 32 + jn) * 72 + kc + quad * 8);
            const f16x8 a1 = *(const f16x8*)(A_lds + (wave * 32 + 16 + jn) * 72 + kc + quad * 8);
#pragma unroll
            for (int nt = 0; nt < 8; nt++) {
                const f16x8 bb = *(const f16x8*)(B_lds + (nt * 16 + jn) * 72 + kc + quad * 8);
                acc[0][nt] = __builtin_amdgcn_mfma_f32_16x16x32_f16(a0, bb, acc[0][nt], 0, 0, 0);
                acc[1][nt] = __builtin_amdgcn_mfma_f32_16x16x32_f16(a1, bb, acc[1][nt], 0, 0, 0);
            }
        }
        __syncthreads();
    }

    // ---- epilogue: bias, assemble (si,g) runs in LDS, 16B vector stores ----
    float bv[8];
#pragma unroll
    for (int nt = 0; nt < 8; nt++)
        bv[nt] = bias[(nt >> 1) * 512 + c0 + (nt & 1) * 16 + jn];

    const int lsi = dir ? (3 - wave) : wave;
#pragma unroll
    for (int mt = 0; mt < 2; mt++) {
#pragma unroll
        for (int r = 0; r < 4; r++) {
            const int b = mt * 16 + quad * 4 + r;
#pragma unroll
            for (int nt = 0; nt < 8; nt++) {
                const int c = (nt & 1) * 16 + jn;
                stage[c * 520 + b * 16 + lsi * 4 + (nt >> 1)] =
                    (_Float16)(acc[mt][nt][r] + bv[nt]);
            }
        }
    }
    __syncthreads();

    const int sidx0 = dir ? (1020 - blockIdx.y * 4) : (blockIdx.y * 4);
    const int sc = sidx0 >> 3;
    const int si0 = sidx0 & 7;  // 0 or 4
#pragma unroll
    for (int it = 0; it < 4; it++) {
        const int p = it * 256 + tid;
        const int c = p & 31;
        const int b = p >> 5;
        const int cglob = c0 + c;
        const int blk = cglob >> 4;
        const int jl = cglob & 15;
        const f16x8* srcp = (const f16x8*)(stage + c * 520 + b * 16);
        const size_t obase =
            ((((size_t)(blk * 32 + b) * 16 + jl) * 128 + sc) * 8 + si0) * 4;
        *(f16x8*)(out + obase) = srcp[0];
        *(f16x8*)(out + obase + 8) = srcp[1];
    }
}

// ---------------------------------------------------------------------------
// Phase 2: persistent bidirectional LSTM recurrence via MFMA.
// EXACT R4 structure — the measured optimum of all variants tried
// (fan-in 16, guarded poll, 2 barriers/step) — with ONE isolated change:
// the re-poison store is issued AFTER the poll loop (before the post-poll
// __syncthreads) instead of before it. In the R4 form the poison store was
// older than the poll loads in the vmcnt FIFO, so the first poll check's
// waitcnt also waited for the store ack (~300-500 cyc on the critical path
// when the first poll hits). Safety guarantee is IDENTICAL: the barrier's
// vmcnt-0 drain still orders the poison strictly before this step's h(s+1)
// store, which is what the consumer-side argument needs.
//
// 64 blocks x 512 threads = 4 chains of 16 (dir x grp); grp owns batch
// rows [grp*16,+16); block owns hidden cols [blk*32,+32) x 4 gates.
// h exchange: sentinel-poisoned 4-slot ring per chain, 4xf16/u64,
// validity = low f16 != 0xFC00 (-inf), slot for step s = s&3.
// ---------------------------------------------------------------------------
__global__ __launch_bounds__(512) void lstm_persist(
    const _Float16* __restrict__ xg_f,
    const _Float16* __restrict__ xg_b,
    const _Float16* __restrict__ WhT_f,
    const _Float16* __restrict__ WhT_b,
    const float* __restrict__ wfc,
    unsigned long long* __restrict__ hring,   // [dir][grp][slot4][2048] u64
    _Float16* __restrict__ part) {

    __shared__ __align__(16) _Float16 h_lds[16 * 520];  // [row16][k512 pad 520]
    __shared__ float red[4 * 16 * 33];                  // [g][row16][col32 pad 33]

    const int tid = threadIdx.x;
    const int bid = blockIdx.x;
    const int dir = bid >> 5;
    const int grp = (bid >> 4) & 1;
    const int blk = bid & 15;

    const _Float16* __restrict__ xg = dir ? xg_b : xg_f;
    const _Float16* __restrict__ WhT = dir ? WhT_b : WhT_f;
    unsigned long long* hp = hring + ((size_t)(dir * 2 + grp)) * 8192;  // [slot4][2048]

    // wave roles
    const int lane = tid & 63;
    const int wave = tid >> 6;
    const int g = wave >> 1;       // gate 0..3
    const int half = wave & 1;     // hidden-16 half within block's 32 cols
    const int jl16 = lane & 15;
    const int quad = lane >> 4;

    // ---- preload Wh B-fragments into registers (once) ----
    f16x8 bfrag[16];
    {
        const _Float16* wcol = WhT + (size_t)(g * 512 + blk * 32 + half * 16 + jl16) * HH;
#pragma unroll
        for (int i = 0; i < 16; i++)
            bfrag[i] = *(const f16x8*)(wcol + i * 32 + quad * 8);
    }

    // gate-thread role: one (row, col) per thread
    const int gb = tid >> 5;       // row within group, 0..15
    const int gc = tid & 31;       // hidden col within block's 32
    float c_reg = 0.0f;
    const float wfc_reg = wfc[dir * 512 + blk * 32 + gc];

    unsigned long long* hl64 = (unsigned long long*)h_lds;
    const int blk32 = blk * 2 + (gc >> 4);
    const int b_glob = grp * 16 + gb;
    const _Float16* xbase =
        xg + (((size_t)(blk32 * 32 + b_glob) * 16 + (gc & 15)) * 128) * 32;

    // producer slot (threads with gc%4==0): u64 covers cols blk*32+gc..+3
    const int prod_idx = gb * 128 + blk * 8 + (gc >> 2);
    const bool is_prod = ((gc & 3) == 0);

    // ---- xg chunk double-buffer: 64 B regs cover 8 steps; prefetch next ----
    f16x8 xcur[4];
    {
        const f16x8* src0 = (const f16x8*)(xbase);
#pragma unroll
        for (int q = 0; q < 4; q++) xcur[q] = src0[q];
    }

    for (int sc = 0; sc < 128; sc++) {
        f16x8 xnxt[4];
        if (sc < 127) {
            const f16x8* srcn = (const f16x8*)(xbase + (sc + 1) * 32);
#pragma unroll
            for (int q = 0; q < 4; q++) xnxt[q] = srcn[q];
        }

#pragma unroll
        for (int si = 0; si < 8; si++) {
            const int s = sc * 8 + si;
            const int t = dir ? (1023 - s) : s;

            // ---- stage h(s): poll sentinel u64s, write arrivals to LDS ----
            // thread's slice: idx = q*512 + tid, q=0..3; row=idx>>7, c4=idx&127
            {
                const unsigned long long* __restrict__ src =
                    hp + (size_t)(s & 3) * 2048;
                unsigned int pend = 0xFu;
                int guard = 0;
                do {
                    unsigned long long v[4];
#pragma unroll
                    for (int q = 0; q < 4; q++)
                        if (pend & (1u << q))
                            v[q] = __hip_atomic_load(src + q * 512 + tid,
                                                     __ATOMIC_RELAXED,
                                                     __HIP_MEMORY_SCOPE_AGENT);
                    unsigned int got = 0;
#pragma unroll
                    for (int q = 0; q < 4; q++) {
                        if ((pend & (1u << q)) &&
                            ((unsigned int)v[q] & 0xFFFFu) != 0xFC00u) {
                            const int idx = q * 512 + tid;
                            hl64[(idx >> 7) * 130 + (idx & 127)] = v[q];
                            got |= (1u << q);
                        }
                    }
                    pend &= ~got;
                    if (pend) {
                        if (got == 0) __builtin_amdgcn_s_sleep(1);
                        if (++guard > (1 << 18)) break;  // fail visibly, never hang
                    }
                } while (pend);
            }

            // ---- re-poison own step-(s-2) positions: issued after the poll
            //      (not in its vmcnt FIFO); drains at the barrier below,
            //      strictly before this step's h(s+1) store — identical
            //      ordering guarantee to the poison-first placement ----
            if (s >= 2 && is_prod)
                __hip_atomic_store(hp + (size_t)((s - 2) & 3) * 2048 + prod_idx,
                                   POISON_U64, __ATOMIC_RELAXED,
                                   __HIP_MEMORY_SCOPE_AGENT);

            __syncthreads();

            // ---- MFMA: preact tile [16row x 16col], 4 independent 4-chains ----
            {
                f32x4 a0 = {0.f, 0.f, 0.f, 0.f};
                f32x4 a1 = {0.f, 0.f, 0.f, 0.f};
                f32x4 a2 = {0.f, 0.f, 0.f, 0.f};
                f32x4 a3 = {0.f, 0.f, 0.f, 0.f};
                const _Float16* hrow = h_lds + jl16 * 520 + quad * 8;
#pragma unroll
                for (int i = 0; i < 4; i++) {
                    const f16x8 h0 = *(const f16x8*)(hrow + 32 * i);
                    const f16x8 h1 = *(const f16x8*)(hrow + 32 * (i + 4));
                    const f16x8 h2 = *(const f16x8*)(hrow + 32 * (i + 8));
                    const f16x8 h3 = *(const f16x8*)(hrow + 32 * (i + 12));
                    a0 = __builtin_amdgcn_mfma_f32_16x16x32_f16(h0, bfrag[i],      a0, 0, 0, 0);
                    a1 = __builtin_amdgcn_mfma_f32_16x16x32_f16(h1, bfrag[i + 4],  a1, 0, 0, 0);
                    a2 = __builtin_amdgcn_mfma_f32_16x16x32_f16(h2, bfrag[i + 8],  a2, 0, 0, 0);
                    a3 = __builtin_amdgcn_mfma_f32_16x16x32_f16(h3, bfrag[i + 12], a3, 0, 0, 0);
                }
                const f32x4 acc = (a0 + a1) + (a2 + a3);
#pragma unroll
                for (int r = 0; r < 4; r++)
                    red[(g * 16 + quad * 4 + r) * 33 + half * 16 + jl16] = acc[r];
            }
            __syncthreads();

            // ---- gate math + h/c update + sentinel h store + FC partial ----
            {
                const float p0 = red[(0 * 16 + gb) * 33 + gc] + (float)xcur[si >> 1][(si & 1) * 4 + 0];
                const float p1 = red[(1 * 16 + gb) * 33 + gc] + (float)xcur[si >> 1][(si & 1) * 4 + 1];
                const float p2 = red[(2 * 16 + gb) * 33 + gc] + (float)xcur[si >> 1][(si & 1) * 4 + 2];
                const float p3 = red[(3 * 16 + gb) * 33 + gc] + (float)xcur[si >> 1][(si & 1) * 4 + 3];

                const float gi = sigm(p0);
                const float gf = sigm(p1);
                const float gc_ = tanh_fast(p2);
                const float go = sigm(p3);
                c_reg = gf * c_reg + gi * gc_;
                const float hval = go * tanh_fast(c_reg);

                // pack 4 consecutive cols into one u64 (two shfls), ONE
                // relaxed agent store per 4 lanes.
                const float hnb = __shfl_xor(hval, 1);
                union { struct { _Float16 lo, hi; } h; unsigned int u; } cvt;
                cvt.h.lo = (_Float16)hval;   // even lanes: (gc, gc+1) in order
                cvt.h.hi = (_Float16)hnb;
                const unsigned int pair2 = __shfl_xor(cvt.u, 2);  // cols gc+2,+3
                if (is_prod) {
                    const unsigned long long pv =
                        ((unsigned long long)pair2 << 32) | (unsigned long long)cvt.u;
                    __hip_atomic_store(hp + (size_t)((s + 1) & 3) * 2048 + prod_idx, pv,
                                       __ATOMIC_RELAXED, __HIP_MEMORY_SCOPE_AGENT);
                }
                // FC partial: reduce over this block's 32 cols (gc = 5 bits)
                float contrib = hval * wfc_reg;
                contrib += __shfl_xor(contrib, 1);
                contrib += __shfl_xor(contrib, 2);
                contrib += __shfl_xor(contrib, 4);
                contrib += __shfl_xor(contrib, 8);
                contrib += __shfl_xor(contrib, 16);
                if (gc == 0)
                    part[(size_t)(t * 32 + b_glob) * 32 + dir * 16 + blk] = (_Float16)contrib;
            }
            // no trailing barrier: next step's LDS stage writes are ordered
            // after this step's MFMA reads by the post-red barrier above.
        }

        if (sc < 127) {
#pragma unroll
            for (int q = 0; q < 4; q++) xcur[q] = xnxt[q];
        }
    }
}

// ---------------------------------------------------------------------------
// Final: out[b][t] = sigmoid(b_fc + sum over 32 partials part[t][b][*])
// ---------------------------------------------------------------------------
__global__ __launch_bounds__(256) void fc_final(const _Float16* __restrict__ part,
                                                const float* __restrict__ b_fc,
                                                float* __restrict__ out) {
    const int i = blockIdx.x * 256 + threadIdx.x;  // i = b*1024 + t
    const int b = i >> 10;
    const int t = i & 1023;
    const f16x8* p = (const f16x8*)(part + (size_t)(t * 32 + b) * 32);
    float acc = b_fc[0];
#pragma unroll
    for (int q = 0; q < 4; q++) {
        const f16x8 v = p[q];
#pragma unroll
        for (int e = 0; e < 8; e++) acc += (float)v[e];
    }
    out[i] = sigm(acc);
}

extern "C" void kernel_launch(void* const* d_in, const int* in_sizes, int n_in,
                              void* d_out, int out_size, void* d_ws, size_t ws_size,
                              hipStream_t stream) {
    const float* x    = (const float*)d_in[0];
    const float* Wx_f = (const float*)d_in[1];
    const float* Wh_f = (const float*)d_in[2];
    const float* b_f  = (const float*)d_in[3];
    const float* Wx_b = (const float*)d_in[4];
    const float* Wh_b = (const float*)d_in[5];
    const float* b_b  = (const float*)d_in[6];
    const float* W_fc = (const float*)d_in[7];
    const float* b_fc = (const float*)d_in[8];
    float* out = (float*)d_out;

    // Workspace layout (bytes):
    //   xgv_f f16 chunk-native          : 134,217,728
    //   xgv_b f16 chunk-native          : 134,217,728
    //   WxT_f f16 [2048][1024]          : 4,194,304   <- `part` (2 MB) aliases
    //   WxT_b f16 [2048][1024]          : 4,194,304   <- hring (256 KB) aliases
    //   WhT_f f16 [2048][512]           : 2,097,152
    //   WhT_b f16 [2048][512]           : 2,097,152
    //   [optional] x16 f16 [B][T][D]    : 67,108,864  (only if ws_size allows)
    // base need 281,018,368 (known to fit); extended 348,127,232 (guarded).
    const size_t XG       = 134217728ULL;
    const size_t WXT_OFF  = 2 * XG;                        // 268,435,456
    const size_t WHT_OFF  = WXT_OFF + 2 * 4194304ULL;      // 276,824,064
    const size_t need     = WHT_OFF + 2 * 2097152ULL;      // 281,018,368
    const size_t X16_OFF  = need;
    const size_t need_ext = need + 67108864ULL;            // 348,127,232
    if (ws_size < need) return;  // fail loudly via mismatch

    uint8_t* ws = (uint8_t*)d_ws;
    _Float16* xg_f = (_Float16*)ws;
    _Float16* xg_b = (_Float16*)(ws + XG);
    _Float16* WxT_f = (_Float16*)(ws + WXT_OFF);
    _Float16* WxT_b = (_Float16*)(ws + WXT_OFF + 4194304ULL);
    _Float16* WhT_f = (_Float16*)(ws + WHT_OFF);
    _Float16* WhT_b = (_Float16*)(ws + WHT_OFF + 2097152ULL);
    _Float16* part  = (_Float16*)(ws + WXT_OFF);                 // alias WxT_f
    unsigned long long* hring =
        (unsigned long long*)(ws + WXT_OFF + 4194304ULL);        // alias WxT_b
    _Float16* x16 = (ws_size >= need_ext) ? (_Float16*)(ws + X16_OFF) : nullptr;

    // pre-transpose weights to f16 [n][k]
    transpose_f16<<<dim3(64, 32), 256, 0, stream>>>(Wx_f, WxT_f, 1024, 2048);
    transpose_f16<<<dim3(64, 32), 256, 0, stream>>>(Wx_b, WxT_b, 1024, 2048);
    transpose_f16<<<dim3(64, 16), 256, 0, stream>>>(Wh_f, WhT_f, 512, 2048);
    transpose_f16<<<dim3(64, 16), 256, 0, stream>>>(Wh_b, WhT_b, 512, 2048);

    // optional: pre-convert x to f16 for the faster gemm A-path
    if (x16) conv_x<<<8192, 256, 0, stream>>>(x, x16);

    // phase 1: input projections (MFMA f16), R4 split-dir grid
    gemm_xg<<<dim3(16, 256, 2), 256, 0, stream>>>(
        x, x16, WxT_f, b_f, WxT_b, b_b, xg_f, xg_b);

    // init sentinel rings (4 chains; slot0 = zeros = valid h(0)) — after
    // gemm_xg since it aliases WxT_b
    init_kernel<<<128, 256, 0, stream>>>(hring);

    // phase 2: persistent recurrence (64 blocks = 4 chains x 16, co-resident)
    lstm_persist<<<64, 512, 0, stream>>>(
        xg_f, xg_b, WhT_f, WhT_b, W_fc, hring, part);

    // epilogue: reduce FC partials + bias + sigmoid
    fc_final<<<(BB * TT) / 256, 256, 0, stream>>>(part, b_fc, out);
}